// Round 8
// baseline (697.313 us; speedup 1.0000x reference)
//
#include <hip/hip_runtime.h>
#include <hip/hip_bf16.h>
#include <math.h>

#define TOKENS 4096
#define KDIM 2048
#define NDIM 2048
#define NEXP 8

#define BM 128
#define BN 128
#define BK 64
#define MAXT 72
#define NBLK (MAXT * 16)   // 1152 = 8 * 144

typedef float  f32x16 __attribute__((ext_vector_type(16)));
typedef short  bf16x8 __attribute__((ext_vector_type(8)));
typedef unsigned short ushort_t;

// ---------- fast-path workspace layout (bytes) ----------
#define WS_WT_HI  0UL
#define WS_WT_LO  67108864UL
#define WS_XH     134217728UL
#define WS_XL     150994944UL
#define WS_META   167772160UL   // int4[4096]
#define WS_RTOK   167837696UL   // int[8192]
#define WS_RWGT   167870464UL   // float[8192]
#define WS_TMETA  167903232UL   // int[161]
#define WS_NEED   167904256UL

// ---------- fallback layout (small ws) ----------
#define FB_META   0UL
#define FB_RTOK   65536UL
#define FB_RWGT   98304UL
#define FB_TMETA  131072UL

#define GLOAD16(g, l) __builtin_amdgcn_global_load_lds( \
    (const __attribute__((address_space(1))) unsigned int*)(g), \
    (__attribute__((address_space(3))) unsigned int*)(l), 16, 0, 0)

__device__ __forceinline__ void cvt8(const float* vv, unsigned int* hp, unsigned int* lp) {
    #pragma unroll
    for (int j = 0; j < 4; ++j) {
        unsigned int b0 = __float_as_uint(vv[2 * j]);
        unsigned int b1 = __float_as_uint(vv[2 * j + 1]);
        unsigned int h0 = b0 >> 16, h1 = b1 >> 16;
        float f0 = __uint_as_float(h0 << 16);
        float f1 = __uint_as_float(h1 << 16);
        unsigned int l0 = __float_as_uint(vv[2 * j] - f0) >> 16;
        unsigned int l1 = __float_as_uint(vv[2 * j + 1] - f1) >> 16;
        hp[j] = h0 | (h1 << 16);
        lp[j] = l0 | (l1 << 16);
    }
}

// ---------------- zero output ----------------
__global__ void k_zero(float* __restrict__ out) {
    long i = (long)blockIdx.x * blockDim.x + threadIdx.x;
    float4* o4 = (float4*)out;
    const long n4 = (long)TOKENS * NDIM / 4;
    for (long j = i; j < n4; j += (long)gridDim.x * blockDim.x)
        o4[j] = make_float4(0.f, 0.f, 0.f, 0.f);
}

// ------- gate + top-2 (one wave/token) + fused x->bf16 hi/lo conversion -------
__global__ __launch_bounds__(256) void k_gate(const float* __restrict__ x,
                                              const float* __restrict__ gw,
                                              const float* __restrict__ gb,
                                              int4* __restrict__ meta,
                                              ushort_t* __restrict__ xh,
                                              ushort_t* __restrict__ xl) {
    int lane = threadIdx.x & 63;
    int wave = threadIdx.x >> 6;
    int t = blockIdx.x * 4 + wave;
    const float* xr = x + (long)t * KDIM;
    const float4* gw4 = (const float4*)gw;
    float acc[8] = {0.f, 0.f, 0.f, 0.f, 0.f, 0.f, 0.f, 0.f};
    #pragma unroll 4
    for (int i = 0; i < KDIM / 64; ++i) {
        int k = i * 64 + lane;
        float xv = xr[k];
        float4 g0 = gw4[k * 2 + 0];
        float4 g1 = gw4[k * 2 + 1];
        acc[0] += xv * g0.x; acc[1] += xv * g0.y;
        acc[2] += xv * g0.z; acc[3] += xv * g0.w;
        acc[4] += xv * g1.x; acc[5] += xv * g1.y;
        acc[6] += xv * g1.z; acc[7] += xv * g1.w;
    }
    #pragma unroll
    for (int e = 0; e < 8; ++e)
        #pragma unroll
        for (int off = 32; off; off >>= 1)
            acc[e] += __shfl_xor(acc[e], off);

    if (lane == 0) {
        float l[8];
        #pragma unroll
        for (int e = 0; e < 8; ++e) l[e] = acc[e] + gb[e];
        int i0 = 0; float b0 = l[0];
        #pragma unroll
        for (int e = 1; e < 8; ++e) if (l[e] > b0) { b0 = l[e]; i0 = e; }
        int i1 = -1; float b1 = -3.4e38f;
        #pragma unroll
        for (int e = 0; e < 8; ++e) if (e != i0 && l[e] > b1) { b1 = l[e]; i1 = e; }
        float w0 = 1.f / (1.f + expf(b1 - b0));
        float w1 = 1.f - w0;
        int4 m;
        m.x = i0; m.y = i1;
        m.z = __float_as_int(w0); m.w = __float_as_int(w1);
        meta[t] = m;
    }

    if (xh) {   // fast path: also emit bf16 hi/lo copy of x (row is L1/L2-hot)
        #pragma unroll
        for (int i = 0; i < 4; ++i) {
            int k8 = (i * 64 + lane) * 8;
            float4 v0 = *(const float4*)(xr + k8);
            float4 v1 = *(const float4*)(xr + k8 + 4);
            float vv[8] = {v0.x, v0.y, v0.z, v0.w, v1.x, v1.y, v1.z, v1.w};
            unsigned int hp[4], lp[4];
            cvt8(vv, hp, lp);
            *(uint4*)(xh + (size_t)t * KDIM + k8) = make_uint4(hp[0], hp[1], hp[2], hp[3]);
            *(uint4*)(xl + (size_t)t * KDIM + k8) = make_uint4(lp[0], lp[1], lp[2], lp[3]);
        }
    }
}

// ------- single-block route: ballot histogram + prefix + tiles + scatter -------
__global__ __launch_bounds__(1024) void k_route(const int4* __restrict__ meta,
                                                int* __restrict__ rtok,
                                                float* __restrict__ rwgt,
                                                int* __restrict__ tmeta) {
    __shared__ int wcnt[16][8];
    __shared__ int wbase[16][8];
    int tid = threadIdx.x;
    int wave = tid >> 6, lane = tid & 63;
    unsigned long long below = (lane == 63) ? 0x7fffffffffffffffULL
                                            : ((1ULL << lane) - 1ULL);
    int4 m[4];
    int c[8] = {0, 0, 0, 0, 0, 0, 0, 0};
    #pragma unroll
    for (int i = 0; i < 4; ++i) {
        m[i] = meta[wave * 256 + i * 64 + lane];
        #pragma unroll
        for (int e = 0; e < 8; ++e) {
            unsigned long long mx = __ballot(m[i].x == e);
            unsigned long long my = __ballot(m[i].y == e);
            c[e] += __popcll(mx) + __popcll(my);
        }
    }
    if (lane == 0)
        #pragma unroll
        for (int e = 0; e < 8; ++e) wcnt[wave][e] = c[e];
    __syncthreads();
    if (tid == 0) {
        int s = 0, nt = 0;
        for (int e = 0; e < 8; ++e) {
            int tot = 0;
            for (int w = 0; w < 16; ++w) { wbase[w][e] = s + tot; tot += wcnt[w][e]; }
            tmeta[145 + e] = s;
            tmeta[153 + e] = tot;
            for (int j = 0; j < tot && nt < MAXT; j += BM) {
                tmeta[nt] = e;
                tmeta[72 + nt] = j;
                ++nt;
            }
            s += tot;
        }
        tmeta[144] = nt;
    }
    __syncthreads();
    int run[8];
    #pragma unroll
    for (int e = 0; e < 8; ++e) run[e] = wbase[wave][e];
    #pragma unroll
    for (int i = 0; i < 4; ++i) {
        int t = wave * 256 + i * 64 + lane;
        #pragma unroll
        for (int e = 0; e < 8; ++e) {
            unsigned long long mx = __ballot(m[i].x == e);
            unsigned long long my = __ballot(m[i].y == e);
            if (m[i].x == e) {
                int p = run[e] + __popcll(mx & below);
                rtok[p] = t; rwgt[p] = __int_as_float(m[i].z);
            }
            if (m[i].y == e) {
                int p = run[e] + __popcll(mx) + __popcll(my & below);
                rtok[p] = t; rwgt[p] = __int_as_float(m[i].w);
            }
            run[e] += __popcll(mx) + __popcll(my);
        }
    }
}

// ------- convert + transpose W[e][k][n] -> Wt[e][n][k] bf16 hi/lo -------
__global__ __launch_bounds__(256) void k_cvt_w(const float* __restrict__ ew,
                                               ushort_t* __restrict__ wth,
                                               ushort_t* __restrict__ wtl) {
    __shared__ float T[64][65];
    int e = blockIdx.z, k0 = blockIdx.x * 64, n0 = blockIdx.y * 64;
    const float* W = ew + ((size_t)e << 22);
    int tid = threadIdx.x;
    #pragma unroll
    for (int i = 0; i < 4; ++i) {
        int idx = tid + i * 256;
        int r = idx >> 4, c4 = idx & 15;
        float4 v = *(const float4*)(W + (size_t)(k0 + r) * NDIM + n0 + c4 * 4);
        T[r][c4 * 4 + 0] = v.x; T[r][c4 * 4 + 1] = v.y;
        T[r][c4 * 4 + 2] = v.z; T[r][c4 * 4 + 3] = v.w;
    }
    __syncthreads();
    #pragma unroll
    for (int i = 0; i < 2; ++i) {
        int idx = tid + i * 256;
        int n = idx >> 3, kc = (idx & 7) * 8;
        float vv[8];
        #pragma unroll
        for (int j = 0; j < 8; ++j) vv[j] = T[kc + j][n];
        unsigned int hp[4], lp[4];
        cvt8(vv, hp, lp);
        size_t o = ((size_t)e << 22) + (size_t)(n0 + n) * KDIM + k0 + kc;
        *(uint4*)(wth + o) = make_uint4(hp[0], hp[1], hp[2], hp[3]);
        *(uint4*)(wtl + o) = make_uint4(lp[0], lp[1], lp[2], lp[3]);
    }
}

// ------- fast grouped GEMM: fragment-order LDS, zero-conflict ds_read -------
// 4 waves; 16 fragment groups per operand. LDS slot ((grp)*64+lane)*16 holds
// the bf16x8 fragment for (wm|wn, kk, q): row = wmj*64+qj*32+(lane&31),
// kbyte = kkj*32+(lane>>5)*16. global_load_lds writes base+lane*16 linearly;
// per-lane SOURCE addresses realize the gather (rule #21: layout = read order).
__global__ __launch_bounds__(256, 2) void k_gemm_fast(
    const ushort_t* __restrict__ xh, const ushort_t* __restrict__ xl,
    const ushort_t* __restrict__ wth, const ushort_t* __restrict__ wtl,
    const float* __restrict__ eb, float* __restrict__ out,
    const int* __restrict__ rtok, const float* __restrict__ rwgt,
    const int* __restrict__ tmeta) {
    __shared__ __align__(16) ushort_t Ah[BM * BK];
    __shared__ __align__(16) ushort_t Al[BM * BK];
    __shared__ __align__(16) ushort_t Bh[BN * BK];
    __shared__ __align__(16) ushort_t Bl[BN * BK];

    int tc = tmeta[144];
    // bijective XCD swizzle: 1152 blocks = 8 * 144; XCD x owns logical
    // [144x, 144x+144) -> consecutive tiles sharing W panels stay on one L2.
    int p = blockIdx.y * MAXT + blockIdx.x;
    int L = (p & 7) * (NBLK / 8) + (p >> 3);
    int bx = L % MAXT;
    int by = L / MAXT;
    if (bx >= tc) return;
    int e    = tmeta[bx];
    int row0 = tmeta[72 + bx];
    int cnt  = tmeta[153 + e];
    int seg  = tmeta[145 + e];
    int nvalid = min(BM, cnt - row0);
    int r0 = seg + row0;
    int gcol0 = by * BN;

    int tid = threadIdx.x;
    int lane = tid & 63, wv = tid >> 6;
    int wm = wv >> 1, wn = wv & 1;

    const char* aSrcH[4]; const char* aSrcL[4];
    const char* bSrcH[4]; const char* bSrcL[4];
    const char* weh = (const char*)(wth + ((size_t)e << 22));
    const char* wel = (const char*)(wtl + ((size_t)e << 22));
    #pragma unroll
    for (int i = 0; i < 4; ++i) {
        int j = wv * 4 + i;                      // fragment-slot group 0..15
        int wmj = j >> 3, kkj = (j >> 1) & 3, qj = j & 1;
        int row = wmj * 64 + qj * 32 + (lane & 31);
        int kbyte = kkj * 32 + ((lane >> 5) << 4);
        int tok = rtok[r0 + min(row, nvalid - 1)];
        aSrcH[i] = (const char*)xh + (size_t)tok * (KDIM * 2) + kbyte;
        aSrcL[i] = (const char*)xl + (size_t)tok * (KDIM * 2) + kbyte;
        size_t nrow = (size_t)(gcol0 + row) * (KDIM * 2) + kbyte;
        bSrcH[i] = weh + nrow;
        bSrcL[i] = wel + nrow;
    }

    f32x16 acc[2][2] = {};

    int aoff = (wm << 13) + lane * 16;   // wave-local fragment base (bytes)
    int boff = (wn << 13) + lane * 16;

    for (int k0b = 0; k0b < KDIM * 2; k0b += BK * 2) {
        __syncthreads();
        #pragma unroll
        for (int i = 0; i < 4; ++i) {
            int ldso = (wv * 4 + i) << 10;   // 1KB per wave-instruction
            GLOAD16(aSrcH[i] + k0b, (char*)Ah + ldso);
            GLOAD16(aSrcL[i] + k0b, (char*)Al + ldso);
            GLOAD16(bSrcH[i] + k0b, (char*)Bh + ldso);
            GLOAD16(bSrcL[i] + k0b, (char*)Bl + ldso);
        }
        __syncthreads();
        #pragma unroll
        for (int kk = 0; kk < 4; ++kk) {
            bf16x8 ah[2], al[2], bh[2], bl[2];
            #pragma unroll
            for (int m = 0; m < 2; ++m) {
                int off = aoff + ((kk * 2 + m) << 10);
                ah[m] = *(const bf16x8*)((const char*)Ah + off);
                al[m] = *(const bf16x8*)((const char*)Al + off);
            }
            #pragma unroll
            for (int n = 0; n < 2; ++n) {
                int off = boff + ((kk * 2 + n) << 10);
                bh[n] = *(const bf16x8*)((const char*)Bh + off);
                bl[n] = *(const bf16x8*)((const char*)Bl + off);
            }
            #pragma unroll
            for (int m = 0; m < 2; ++m)
                #pragma unroll
                for (int n = 0; n < 2; ++n) {
                    acc[m][n] = __builtin_amdgcn_mfma_f32_32x32x16_bf16(ah[m], bh[n], acc[m][n], 0, 0, 0);
                    acc[m][n] = __builtin_amdgcn_mfma_f32_32x32x16_bf16(ah[m], bl[n], acc[m][n], 0, 0, 0);
                    acc[m][n] = __builtin_amdgcn_mfma_f32_32x32x16_bf16(al[m], bh[n], acc[m][n], 0, 0, 0);
                }
        }
    }

    float biasv[2]; int coln[2];
    #pragma unroll
    for (int n = 0; n < 2; ++n) {
        coln[n] = gcol0 + wn * 64 + n * 32 + (lane & 31);
        biasv[n] = eb[e * NDIM + coln[n]];
    }
    #pragma unroll
    for (int m = 0; m < 2; ++m) {
        #pragma unroll
        for (int reg = 0; reg < 16; ++reg) {
            int rl = wm * 64 + m * 32 + (reg & 3) + 8 * (reg >> 2) + 4 * (lane >> 5);
            if (rl < nvalid) {
                int tok = rtok[r0 + rl];
                float w = rwgt[r0 + rl];
                #pragma unroll
                for (int n = 0; n < 2; ++n) {
                    float val = (acc[m][n][reg] + biasv[n]) * w;
                    atomicAdd(out + (long)tok * NDIM + coln[n], val);
                }
            }
        }
    }
}

// ------- fallback GEMM (fp32 inputs, inline cvt; proven path) -------
__global__ __launch_bounds__(256, 2) void k_gemm_fb(
    const float* __restrict__ x, const float* __restrict__ ew,
    const float* __restrict__ eb, float* __restrict__ out,
    const int* __restrict__ rtok, const float* __restrict__ rwgt,
    const int* __restrict__ tmeta) {
    __shared__ __align__(16) ushort_t Ah[BM * BK];
    __shared__ __align__(16) ushort_t Al[BM * BK];
    __shared__ __align__(16) ushort_t Bh[BN * BK];
    __shared__ __align__(16) ushort_t Bl[BN * BK];

    int tc = tmeta[144];
    int bx = blockIdx.x;
    if (bx >= tc) return;
    int e    = tmeta[bx];
    int row0 = tmeta[72 + bx];
    int cnt  = tmeta[153 + e];
    int seg  = tmeta[145 + e];
    int nvalid = min(BM, cnt - row0);
    int r0 = seg + row0;
    int gcol0 = blockIdx.y * BN;
    const float* W = ew + (long)e * KDIM * NDIM;

    int tid = threadIdx.x;
    int lane = tid & 63, wv = tid >> 6;
    int wm = wv >> 1, wn = wv & 1;

    f32x16 acc[2][2] = {};

    for (int k0 = 0; k0 < KDIM; k0 += BK) {
        __syncthreads();
        #pragma unroll
        for (int i = 0; i < 4; ++i) {
            int c = tid + i * 256;
            int r = c >> 3;
            int kc = (c & 7) * 8;
            int tok = rtok[r0 + min(r, nvalid - 1)];
            const float* src = x + (long)tok * KDIM + k0 + kc;
            float4 v0 = ((const float4*)src)[0];
            float4 v1 = ((const float4*)src)[1];
            float vv[8] = {v0.x, v0.y, v0.z, v0.w, v1.x, v1.y, v1.z, v1.w};
            unsigned int hp[4], lp[4];
            cvt8(vv, hp, lp);
            int off = (r * 128 + kc * 2) ^ ((r & 7) << 4);
            *(uint4*)((char*)Ah + off) = make_uint4(hp[0], hp[1], hp[2], hp[3]);
            *(uint4*)((char*)Al + off) = make_uint4(lp[0], lp[1], lp[2], lp[3]);
        }
        #pragma unroll
        for (int i = 0; i < 4; ++i) {
            int c = tid + i * 256;
            int n = c & 127;
            int kg = c >> 7;
            const float* src = W + (long)(k0 + kg * 8) * NDIM + gcol0 + n;
            float vv[8];
            #pragma unroll
            for (int j = 0; j < 8; ++j) vv[j] = src[(long)j * NDIM];
            unsigned int hp[4], lp[4];
            cvt8(vv, hp, lp);
            int off = (n * 128 + kg * 16) ^ ((n & 7) << 4);
            *(uint4*)((char*)Bh + off) = make_uint4(hp[0], hp[1], hp[2], hp[3]);
            *(uint4*)((char*)Bl + off) = make_uint4(lp[0], lp[1], lp[2], lp[3]);
        }
        __syncthreads();
        #pragma unroll
        for (int kk = 0; kk < 4; ++kk) {
            int krun2 = kk * 32 + ((lane >> 5) << 4);
            bf16x8 ah[2], al[2], bh[2], bl[2];
            #pragma unroll
            for (int m = 0; m < 2; ++m) {
                int row = wm * 64 + m * 32 + (lane & 31);
                int off = row * 128 + (krun2 ^ ((row & 7) << 4));
                ah[m] = *(const bf16x8*)((const char*)Ah + off);
                al[m] = *(const bf16x8*)((const char*)Al + off);
            }
            #pragma unroll
            for (int n = 0; n < 2; ++n) {
                int row = wn * 64 + n * 32 + (lane & 31);
                int off = row * 128 + (krun2 ^ ((row & 7) << 4));
                bh[n] = *(const bf16x8*)((const char*)Bh + off);
                bl[n] = *(const bf16x8*)((const char*)Bl + off);
            }
            #pragma unroll
            for (int m = 0; m < 2; ++m)
                #pragma unroll
                for (int n = 0; n < 2; ++n) {
                    acc[m][n] = __builtin_amdgcn_mfma_f32_32x32x16_bf16(ah[m], bh[n], acc[m][n], 0, 0, 0);
                    acc[m][n] = __builtin_amdgcn_mfma_f32_32x32x16_bf16(ah[m], bl[n], acc[m][n], 0, 0, 0);
                    acc[m][n] = __builtin_amdgcn_mfma_f32_32x32x16_bf16(al[m], bh[n], acc[m][n], 0, 0, 0);
                }
        }
    }

    float biasv[2]; int coln[2];
    #pragma unroll
    for (int n = 0; n < 2; ++n) {
        coln[n] = gcol0 + wn * 64 + n * 32 + (lane & 31);
        biasv[n] = eb[e * NDIM + coln[n]];
    }
    #pragma unroll
    for (int m = 0; m < 2; ++m) {
        #pragma unroll
        for (int reg = 0; reg < 16; ++reg) {
            int rl = wm * 64 + m * 32 + (reg & 3) + 8 * (reg >> 2) + 4 * (lane >> 5);
            if (rl < nvalid) {
                int tok = rtok[r0 + rl];
                float w = rwgt[r0 + rl];
                #pragma unroll
                for (int n = 0; n < 2; ++n) {
                    float val = (acc[m][n][reg] + biasv[n]) * w;
                    atomicAdd(out + (long)tok * NDIM + coln[n], val);
                }
            }
        }
    }
}

extern "C" void kernel_launch(void* const* d_in, const int* in_sizes, int n_in,
                              void* d_out, int out_size, void* d_ws, size_t ws_size,
                              hipStream_t stream) {
    const float* x  = (const float*)d_in[0];
    const float* ew = (const float*)d_in[1];
    const float* eb = (const float*)d_in[2];
    const float* gw = (const float*)d_in[3];
    const float* gb = (const float*)d_in[4];
    float* out = (float*)d_out;
    char* ws = (char*)d_ws;

    if (ws_size >= WS_NEED) {
        ushort_t* wth = (ushort_t*)(ws + WS_WT_HI);
        ushort_t* wtl = (ushort_t*)(ws + WS_WT_LO);
        ushort_t* xh  = (ushort_t*)(ws + WS_XH);
        ushort_t* xl  = (ushort_t*)(ws + WS_XL);
        int4*  meta  = (int4*)(ws + WS_META);
        int*   rtok  = (int*)(ws + WS_RTOK);
        float* rwgt  = (float*)(ws + WS_RWGT);
        int*   tmeta = (int*)(ws + WS_TMETA);

        k_zero<<<dim3(2048), dim3(256), 0, stream>>>(out);
        k_gate<<<dim3(TOKENS / 4), dim3(256), 0, stream>>>(x, gw, gb, meta, xh, xl);
        k_route<<<dim3(1), dim3(1024), 0, stream>>>(meta, rtok, rwgt, tmeta);
        k_cvt_w<<<dim3(32, 32, 8), dim3(256), 0, stream>>>(ew, wth, wtl);
        k_gemm_fast<<<dim3(MAXT, 16), dim3(256), 0, stream>>>(
            xh, xl, wth, wtl, eb, out, rtok, rwgt, tmeta);
    } else {
        int4*  meta  = (int4*)(ws + FB_META);
        int*   rtok  = (int*)(ws + FB_RTOK);
        float* rwgt  = (float*)(ws + FB_RWGT);
        int*   tmeta = (int*)(ws + FB_TMETA);

        k_zero<<<dim3(2048), dim3(256), 0, stream>>>(out);
        k_gate<<<dim3(TOKENS / 4), dim3(256), 0, stream>>>(x, gw, gb, meta,
                                                           (ushort_t*)0, (ushort_t*)0);
        k_route<<<dim3(1), dim3(1024), 0, stream>>>(meta, rtok, rwgt, tmeta);
        k_gemm_fb<<<dim3(MAXT, 16), dim3(256), 0, stream>>>(
            x, ew, eb, out, rtok, rwgt, tmeta);
    }
}

// Round 10
// 453.296 us; speedup vs baseline: 1.5383x; 1.5383x over previous
//
#include <hip/hip_runtime.h>
#include <hip/hip_bf16.h>
#include <math.h>

#define TOKENS 4096
#define KDIM 2048
#define NDIM 2048
#define NEXP 8

#define BM 128
#define BN 128
#define BK 64
#define MAXT 72

typedef float  f32x16 __attribute__((ext_vector_type(16)));
typedef short  bf16x8 __attribute__((ext_vector_type(8)));
typedef unsigned short ushort_t;

// ---------- fast-path workspace layout (bytes) ----------
#define WS_WT_HI  0UL
#define WS_XH     134217728UL
#define WS_XL     150994944UL
#define WS_META   167772160UL   // int4[4096]
#define WS_RTOK   167837696UL   // int[8192]
#define WS_RWGT   167870464UL   // float[8192]
#define WS_TMETA  167903232UL   // int[161]
#define WS_NEED   167904256UL

// ---------- fallback layout (small ws) ----------
#define FB_META   0UL
#define FB_RTOK   65536UL
#define FB_RWGT   98304UL
#define FB_TMETA  131072UL

#define GLOAD16(g, l) __builtin_amdgcn_global_load_lds( \
    (const __attribute__((address_space(1))) unsigned int*)(g), \
    (__attribute__((address_space(3))) unsigned int*)(l), 16, 0, 0)

__device__ __forceinline__ void cvt8(const float* vv, unsigned int* hp, unsigned int* lp) {
    #pragma unroll
    for (int j = 0; j < 4; ++j) {
        unsigned int b0 = __float_as_uint(vv[2 * j]);
        unsigned int b1 = __float_as_uint(vv[2 * j + 1]);
        unsigned int h0 = b0 >> 16, h1 = b1 >> 16;
        float f0 = __uint_as_float(h0 << 16);
        float f1 = __uint_as_float(h1 << 16);
        unsigned int l0 = __float_as_uint(vv[2 * j] - f0) >> 16;
        unsigned int l1 = __float_as_uint(vv[2 * j + 1] - f1) >> 16;
        hp[j] = h0 | (h1 << 16);
        lp[j] = l0 | (l1 << 16);
    }
}

__device__ __forceinline__ void cvt8h(const float* vv, unsigned int* hp) {
    #pragma unroll
    for (int j = 0; j < 4; ++j) {
        unsigned int h0 = __float_as_uint(vv[2 * j]) >> 16;
        unsigned int h1 = __float_as_uint(vv[2 * j + 1]) >> 16;
        hp[j] = h0 | (h1 << 16);
    }
}

// ---------------- zero output ----------------
__global__ void k_zero(float* __restrict__ out) {
    long i = (long)blockIdx.x * blockDim.x + threadIdx.x;
    float4* o4 = (float4*)out;
    const long n4 = (long)TOKENS * NDIM / 4;
    for (long j = i; j < n4; j += (long)gridDim.x * blockDim.x)
        o4[j] = make_float4(0.f, 0.f, 0.f, 0.f);
}

// ------- gate + top-2 (one wave/token) + fused x->bf16 hi/lo conversion -------
__global__ __launch_bounds__(256) void k_gate(const float* __restrict__ x,
                                              const float* __restrict__ gw,
                                              const float* __restrict__ gb,
                                              int4* __restrict__ meta,
                                              ushort_t* __restrict__ xh,
                                              ushort_t* __restrict__ xl) {
    int lane = threadIdx.x & 63;
    int wave = threadIdx.x >> 6;
    int t = blockIdx.x * 4 + wave;
    const float* xr = x + (long)t * KDIM;
    const float4* gw4 = (const float4*)gw;
    float acc[8] = {0.f, 0.f, 0.f, 0.f, 0.f, 0.f, 0.f, 0.f};
    #pragma unroll 4
    for (int i = 0; i < KDIM / 64; ++i) {
        int k = i * 64 + lane;
        float xv = xr[k];
        float4 g0 = gw4[k * 2 + 0];
        float4 g1 = gw4[k * 2 + 1];
        acc[0] += xv * g0.x; acc[1] += xv * g0.y;
        acc[2] += xv * g0.z; acc[3] += xv * g0.w;
        acc[4] += xv * g1.x; acc[5] += xv * g1.y;
        acc[6] += xv * g1.z; acc[7] += xv * g1.w;
    }
    #pragma unroll
    for (int e = 0; e < 8; ++e)
        #pragma unroll
        for (int off = 32; off; off >>= 1)
            acc[e] += __shfl_xor(acc[e], off);

    if (lane == 0) {
        float l[8];
        #pragma unroll
        for (int e = 0; e < 8; ++e) l[e] = acc[e] + gb[e];
        int i0 = 0; float b0 = l[0];
        #pragma unroll
        for (int e = 1; e < 8; ++e) if (l[e] > b0) { b0 = l[e]; i0 = e; }
        int i1 = -1; float b1 = -3.4e38f;
        #pragma unroll
        for (int e = 0; e < 8; ++e) if (e != i0 && l[e] > b1) { b1 = l[e]; i1 = e; }
        float w0 = 1.f / (1.f + expf(b1 - b0));
        float w1 = 1.f - w0;
        int4 m;
        m.x = i0; m.y = i1;
        m.z = __float_as_int(w0); m.w = __float_as_int(w1);
        meta[t] = m;
    }

    if (xh) {   // fast path: also emit bf16 hi/lo copy of x (row is L1/L2-hot)
        #pragma unroll
        for (int i = 0; i < 4; ++i) {
            int k8 = (i * 64 + lane) * 8;
            float4 v0 = *(const float4*)(xr + k8);
            float4 v1 = *(const float4*)(xr + k8 + 4);
            float vv[8] = {v0.x, v0.y, v0.z, v0.w, v1.x, v1.y, v1.z, v1.w};
            unsigned int hp[4], lp[4];
            cvt8(vv, hp, lp);
            *(uint4*)(xh + (size_t)t * KDIM + k8) = make_uint4(hp[0], hp[1], hp[2], hp[3]);
            *(uint4*)(xl + (size_t)t * KDIM + k8) = make_uint4(lp[0], lp[1], lp[2], lp[3]);
        }
    }
}

// ------- single-block route: ballot histogram + prefix + tiles + scatter -------
__global__ __launch_bounds__(1024) void k_route(const int4* __restrict__ meta,
                                                int* __restrict__ rtok,
                                                float* __restrict__ rwgt,
                                                int* __restrict__ tmeta) {
    __shared__ int wcnt[16][8];
    __shared__ int wbase[16][8];
    int tid = threadIdx.x;
    int wave = tid >> 6, lane = tid & 63;
    unsigned long long below = (lane == 63) ? 0x7fffffffffffffffULL
                                            : ((1ULL << lane) - 1ULL);
    int4 m[4];
    int c[8] = {0, 0, 0, 0, 0, 0, 0, 0};
    #pragma unroll
    for (int i = 0; i < 4; ++i) {
        m[i] = meta[wave * 256 + i * 64 + lane];
        #pragma unroll
        for (int e = 0; e < 8; ++e) {
            unsigned long long mx = __ballot(m[i].x == e);
            unsigned long long my = __ballot(m[i].y == e);
            c[e] += __popcll(mx) + __popcll(my);
        }
    }
    if (lane == 0)
        #pragma unroll
        for (int e = 0; e < 8; ++e) wcnt[wave][e] = c[e];
    __syncthreads();
    if (tid == 0) {
        int s = 0, nt = 0;
        for (int e = 0; e < 8; ++e) {
            int tot = 0;
            for (int w = 0; w < 16; ++w) { wbase[w][e] = s + tot; tot += wcnt[w][e]; }
            tmeta[145 + e] = s;
            tmeta[153 + e] = tot;
            for (int j = 0; j < tot && nt < MAXT; j += BM) {
                tmeta[nt] = e;
                tmeta[72 + nt] = j;
                ++nt;
            }
            s += tot;
        }
        tmeta[144] = nt;
    }
    __syncthreads();
    int run[8];
    #pragma unroll
    for (int e = 0; e < 8; ++e) run[e] = wbase[wave][e];
    #pragma unroll
    for (int i = 0; i < 4; ++i) {
        int t = wave * 256 + i * 64 + lane;
        #pragma unroll
        for (int e = 0; e < 8; ++e) {
            unsigned long long mx = __ballot(m[i].x == e);
            unsigned long long my = __ballot(m[i].y == e);
            if (m[i].x == e) {
                int p = run[e] + __popcll(mx & below);
                rtok[p] = t; rwgt[p] = __int_as_float(m[i].z);
            }
            if (m[i].y == e) {
                int p = run[e] + __popcll(mx) + __popcll(my & below);
                rtok[p] = t; rwgt[p] = __int_as_float(m[i].w);
            }
            run[e] += __popcll(mx) + __popcll(my);
        }
    }
}

// ------- convert + transpose W[e][k][n] -> Wt[e][n][k] bf16 HI ONLY -------
__global__ __launch_bounds__(256) void k_cvt_w(const float* __restrict__ ew,
                                               ushort_t* __restrict__ wth) {
    __shared__ float T[64][65];
    int e = blockIdx.z, k0 = blockIdx.x * 64, n0 = blockIdx.y * 64;
    const float* W = ew + ((size_t)e << 22);
    int tid = threadIdx.x;
    #pragma unroll
    for (int i = 0; i < 4; ++i) {
        int idx = tid + i * 256;
        int r = idx >> 4, c4 = idx & 15;
        float4 v = *(const float4*)(W + (size_t)(k0 + r) * NDIM + n0 + c4 * 4);
        T[r][c4 * 4 + 0] = v.x; T[r][c4 * 4 + 1] = v.y;
        T[r][c4 * 4 + 2] = v.z; T[r][c4 * 4 + 3] = v.w;
    }
    __syncthreads();
    #pragma unroll
    for (int i = 0; i < 2; ++i) {
        int idx = tid + i * 256;
        int n = idx >> 3, kc = (idx & 7) * 8;
        float vv[8];
        #pragma unroll
        for (int j = 0; j < 8; ++j) vv[j] = T[kc + j][n];
        unsigned int hp[4];
        cvt8h(vv, hp);
        size_t o = ((size_t)e << 22) + (size_t)(n0 + n) * KDIM + k0 + kc;
        *(uint4*)(wth + o) = make_uint4(hp[0], hp[1], hp[2], hp[3]);
    }
}

// ------- fast grouped GEMM: coalesced gload_lds + XOR swizzle (proven 347us
// structure), W-hi only (x kept hi/lo -> 2 MFMAs per update), 48KB LDS -------
__global__ __launch_bounds__(256, 2) void k_gemm_fast(
    const ushort_t* __restrict__ xh, const ushort_t* __restrict__ xl,
    const ushort_t* __restrict__ wth,
    const float* __restrict__ eb, float* __restrict__ out,
    const int* __restrict__ rtok, const float* __restrict__ rwgt,
    const int* __restrict__ tmeta) {
    __shared__ __align__(16) ushort_t Ah[BM * BK];
    __shared__ __align__(16) ushort_t Al[BM * BK];
    __shared__ __align__(16) ushort_t Bh[BN * BK];

    int tc = tmeta[144];
    // XCD chunking with bx-fastest order: XCD x owns bx in [9x, 9x+9) for all
    // by; concurrent blocks on one XCD then share ~7 by-panels (~3.5MB of W-hi,
    // fits the 4MB per-XCD L2) instead of a whole expert's 8MB.
    int p = blockIdx.y * MAXT + blockIdx.x;
    int xcd = p & 7;
    int j = p >> 3;                 // 0..143
    int bx = xcd * (MAXT / 8) + (j % (MAXT / 8));
    int by = j / (MAXT / 8);        // 0..15
    if (bx >= tc) return;
    int e    = tmeta[bx];
    int row0 = tmeta[72 + bx];
    int cnt  = tmeta[153 + e];
    int seg  = tmeta[145 + e];
    int nvalid = min(BM, cnt - row0);
    int r0 = seg + row0;
    int gcol0 = by * BN;

    int tid = threadIdx.x;
    int lane = tid & 63, wv = tid >> 6;
    int wm = wv >> 1, wn = wv & 1;

    int lr = lane >> 3;            // row within 8-row group
    int lb = (lane & 7) * 16;      // byte within the 128B k-window
    int sb = lb ^ (lr << 4);       // inverse-swizzled source byte offset

    const char* aSrcH[4]; const char* aSrcL[4];
    const char* bSrcH[4];
    const char* weh = (const char*)(wth + ((size_t)e << 22));
    #pragma unroll
    for (int i = 0; i < 4; ++i) {
        int r = (wv * 4 + i) * 8 + lr;
        int tok = rtok[r0 + min(r, nvalid - 1)];
        aSrcH[i] = (const char*)xh + (size_t)tok * (KDIM * 2) + sb;
        aSrcL[i] = (const char*)xl + (size_t)tok * (KDIM * 2) + sb;
        bSrcH[i] = weh + (size_t)(gcol0 + r) * (KDIM * 2) + sb;
    }

    f32x16 acc[2][2] = {};

    for (int k0b = 0; k0b < KDIM * 2; k0b += BK * 2) {
        __syncthreads();
        #pragma unroll
        for (int i = 0; i < 4; ++i) {
            int ldso = (wv * 4 + i) << 10;   // 1KB per wave-instruction
            GLOAD16(aSrcH[i] + k0b, (char*)Ah + ldso);
            GLOAD16(aSrcL[i] + k0b, (char*)Al + ldso);
            GLOAD16(bSrcH[i] + k0b, (char*)Bh + ldso);
        }
        __syncthreads();
        #pragma unroll
        for (int kk = 0; kk < 4; ++kk) {
            int krun2 = kk * 32 + ((lane >> 5) << 4);   // byte col offset
            bf16x8 ah[2], al[2], bh[2];
            #pragma unroll
            for (int m = 0; m < 2; ++m) {
                int row = wm * 64 + m * 32 + (lane & 31);
                int off = row * 128 + (krun2 ^ ((row & 7) << 4));
                ah[m] = *(const bf16x8*)((const char*)Ah + off);
                al[m] = *(const bf16x8*)((const char*)Al + off);
            }
            #pragma unroll
            for (int n = 0; n < 2; ++n) {
                int row = wn * 64 + n * 32 + (lane & 31);
                int off = row * 128 + (krun2 ^ ((row & 7) << 4));
                bh[n] = *(const bf16x8*)((const char*)Bh + off);
            }
            #pragma unroll
            for (int m = 0; m < 2; ++m)
                #pragma unroll
                for (int n = 0; n < 2; ++n) {
                    acc[m][n] = __builtin_amdgcn_mfma_f32_32x32x16_bf16(ah[m], bh[n], acc[m][n], 0, 0, 0);
                    acc[m][n] = __builtin_amdgcn_mfma_f32_32x32x16_bf16(al[m], bh[n], acc[m][n], 0, 0, 0);
                }
        }
    }

    float biasv[2]; int coln[2];
    #pragma unroll
    for (int n = 0; n < 2; ++n) {
        coln[n] = gcol0 + wn * 64 + n * 32 + (lane & 31);
        biasv[n] = eb[e * NDIM + coln[n]];
    }
    #pragma unroll
    for (int m = 0; m < 2; ++m) {
        #pragma unroll
        for (int reg = 0; reg < 16; ++reg) {
            int rl = wm * 64 + m * 32 + (reg & 3) + 8 * (reg >> 2) + 4 * (lane >> 5);
            if (rl < nvalid) {
                int tok = rtok[r0 + rl];
                float w = rwgt[r0 + rl];
                #pragma unroll
                for (int n = 0; n < 2; ++n) {
                    float val = (acc[m][n][reg] + biasv[n]) * w;
                    atomicAdd(out + (long)tok * NDIM + coln[n], val);
                }
            }
        }
    }
}

// ------- fallback GEMM (fp32 inputs, inline cvt; W-hi only) -------
__global__ __launch_bounds__(256, 2) void k_gemm_fb(
    const float* __restrict__ x, const float* __restrict__ ew,
    const float* __restrict__ eb, float* __restrict__ out,
    const int* __restrict__ rtok, const float* __restrict__ rwgt,
    const int* __restrict__ tmeta) {
    __shared__ __align__(16) ushort_t Ah[BM * BK];
    __shared__ __align__(16) ushort_t Al[BM * BK];
    __shared__ __align__(16) ushort_t Bh[BN * BK];

    int tc = tmeta[144];
    int bx = blockIdx.x;
    if (bx >= tc) return;
    int e    = tmeta[bx];
    int row0 = tmeta[72 + bx];
    int cnt  = tmeta[153 + e];
    int seg  = tmeta[145 + e];
    int nvalid = min(BM, cnt - row0);
    int r0 = seg + row0;
    int gcol0 = blockIdx.y * BN;
    const float* W = ew + (long)e * KDIM * NDIM;

    int tid = threadIdx.x;
    int lane = tid & 63, wv = tid >> 6;
    int wm = wv >> 1, wn = wv & 1;

    f32x16 acc[2][2] = {};

    for (int k0 = 0; k0 < KDIM; k0 += BK) {
        __syncthreads();
        #pragma unroll
        for (int i = 0; i < 4; ++i) {
            int c = tid + i * 256;
            int r = c >> 3;
            int kc = (c & 7) * 8;
            int tok = rtok[r0 + min(r, nvalid - 1)];
            const float* src = x + (long)tok * KDIM + k0 + kc;
            float4 v0 = ((const float4*)src)[0];
            float4 v1 = ((const float4*)src)[1];
            float vv[8] = {v0.x, v0.y, v0.z, v0.w, v1.x, v1.y, v1.z, v1.w};
            unsigned int hp[4], lp[4];
            cvt8(vv, hp, lp);
            int off = (r * 128 + kc * 2) ^ ((r & 7) << 4);
            *(uint4*)((char*)Ah + off) = make_uint4(hp[0], hp[1], hp[2], hp[3]);
            *(uint4*)((char*)Al + off) = make_uint4(lp[0], lp[1], lp[2], lp[3]);
        }
        #pragma unroll
        for (int i = 0; i < 4; ++i) {
            int c = tid + i * 256;
            int n = c & 127;
            int kg = c >> 7;
            const float* src = W + (long)(k0 + kg * 8) * NDIM + gcol0 + n;
            float vv[8];
            #pragma unroll
            for (int j = 0; j < 8; ++j) vv[j] = src[(long)j * NDIM];
            unsigned int hp[4];
            cvt8h(vv, hp);
            int off = (n * 128 + kg * 16) ^ ((n & 7) << 4);
            *(uint4*)((char*)Bh + off) = make_uint4(hp[0], hp[1], hp[2], hp[3]);
        }
        __syncthreads();
        #pragma unroll
        for (int kk = 0; kk < 4; ++kk) {
            int krun2 = kk * 32 + ((lane >> 5) << 4);
            bf16x8 ah[2], al[2], bh[2];
            #pragma unroll
            for (int m = 0; m < 2; ++m) {
                int row = wm * 64 + m * 32 + (lane & 31);
                int off = row * 128 + (krun2 ^ ((row & 7) << 4));
                ah[m] = *(const bf16x8*)((const char*)Ah + off);
                al[m] = *(const bf16x8*)((const char*)Al + off);
            }
            #pragma unroll
            for (int n = 0; n < 2; ++n) {
                int row = wn * 64 + n * 32 + (lane & 31);
                int off = row * 128 + (krun2 ^ ((row & 7) << 4));
                bh[n] = *(const bf16x8*)((const char*)Bh + off);
            }
            #pragma unroll
            for (int m = 0; m < 2; ++m)
                #pragma unroll
                for (int n = 0; n < 2; ++n) {
                    acc[m][n] = __builtin_amdgcn_mfma_f32_32x32x16_bf16(ah[m], bh[n], acc[m][n], 0, 0, 0);
                    acc[m][n] = __builtin_amdgcn_mfma_f32_32x32x16_bf16(al[m], bh[n], acc[m][n], 0, 0, 0);
                }
        }
    }

    float biasv[2]; int coln[2];
    #pragma unroll
    for (int n = 0; n < 2; ++n) {
        coln[n] = gcol0 + wn * 64 + n * 32 + (lane & 31);
        biasv[n] = eb[e * NDIM + coln[n]];
    }
    #pragma unroll
    for (int m = 0; m < 2; ++m) {
        #pragma unroll
        for (int reg = 0; reg < 16; ++reg) {
            int rl = wm * 64 + m * 32 + (reg & 3) + 8 * (reg >> 2) + 4 * (lane >> 5);
            if (rl < nvalid) {
                int tok = rtok[r0 + rl];
                float w = rwgt[r0 + rl];
                #pragma unroll
                for (int n = 0; n < 2; ++n) {
                    float val = (acc[m][n][reg] + biasv[n]) * w;
                    atomicAdd(out + (long)tok * NDIM + coln[n], val);
                }
            }
        }
    }
}

extern "C" void kernel_launch(void* const* d_in, const int* in_sizes, int n_in,
                              void* d_out, int out_size, void* d_ws, size_t ws_size,
                              hipStream_t stream) {
    const float* x  = (const float*)d_in[0];
    const float* ew = (const float*)d_in[1];
    const float* eb = (const float*)d_in[2];
    const float* gw = (const float*)d_in[3];
    const float* gb = (const float*)d_in[4];
    float* out = (float*)d_out;
    char* ws = (char*)d_ws;

    if (ws_size >= WS_NEED) {
        ushort_t* wth = (ushort_t*)(ws + WS_WT_HI);
        ushort_t* xh  = (ushort_t*)(ws + WS_XH);
        ushort_t* xl  = (ushort_t*)(ws + WS_XL);
        int4*  meta  = (int4*)(ws + WS_META);
        int*   rtok  = (int*)(ws + WS_RTOK);
        float* rwgt  = (float*)(ws + WS_RWGT);
        int*   tmeta = (int*)(ws + WS_TMETA);

        k_zero<<<dim3(2048), dim3(256), 0, stream>>>(out);
        k_gate<<<dim3(TOKENS / 4), dim3(256), 0, stream>>>(x, gw, gb, meta, xh, xl);
        k_route<<<dim3(1), dim3(1024), 0, stream>>>(meta, rtok, rwgt, tmeta);
        k_cvt_w<<<dim3(32, 32, 8), dim3(256), 0, stream>>>(ew, wth);
        k_gemm_fast<<<dim3(MAXT, 16), dim3(256), 0, stream>>>(
            xh, xl, wth, eb, out, rtok, rwgt, tmeta);
    } else {
        int4*  meta  = (int4*)(ws + FB_META);
        int*   rtok  = (int*)(ws + FB_RTOK);
        float* rwgt  = (float*)(ws + FB_RWGT);
        int*   tmeta = (int*)(ws + FB_TMETA);

        k_zero<<<dim3(2048), dim3(256), 0, stream>>>(out);
        k_gate<<<dim3(TOKENS / 4), dim3(256), 0, stream>>>(x, gw, gb, meta,
                                                           (ushort_t*)0, (ushort_t*)0);
        k_route<<<dim3(1), dim3(1024), 0, stream>>>(meta, rtok, rwgt, tmeta);
        k_gemm_fb<<<dim3(MAXT, 16), dim3(256), 0, stream>>>(
            x, ew, eb, out, rtok, rwgt, tmeta);
    }
}